// Round 11
// baseline (394.214 us; speedup 1.0000x reference)
//
#include <hip/hip_runtime.h>

// Capsule routing: B=256, J=2, N=6912, E=16, D=8, 2 routing iters. All fp32.
//   pass1: s1[b,j,e] = sum_n u_hat;  v1 = squash(0.5*s1)
//   pass2: l[j,n] = sum_e v1*u_hat; c = sigmoid(l0-l1); s2 = sum_n c*u_hat
//   out = squash(s2) fp32 [256,2,16].
// R11: R10's wave-uniform LDS broadcast is write-back-bound (~12cyc/ds_read
// regardless of broadcast): 32 reads/n/wave = ~17us/pass at the CU LDS unit.
// Fix: 2 batch elems per lane (b, b+64) -> each W read feeds 16 FMAs, LDS
// traffic halves. 128-thr blocks (2 waves) x 18n x 128b; grid (384,2)=768.
// Registers counted: pass2 peak ~235 <= 256 cap (launch_bounds(128,2)).
#define B_ 256
#define J_ 2
#define N_ 6912
#define E_ 16
#define D_ 8
#define NPW 9       // n per wave
#define NBK 18      // n per block
#define NCHUNK 384  // N_/NBK; grid (NCHUNK, 2)

__device__ __forceinline__ float dot8(float4 wa, float4 wb, float4 xa, float4 xb){
  float a;
  a = wa.x*xa.x;           a = fmaf(wa.y, xa.y, a);
  a = fmaf(wa.z, xa.z, a); a = fmaf(wa.w, xa.w, a);
  a = fmaf(wb.x, xb.x, a); a = fmaf(wb.y, xb.y, a);
  a = fmaf(wb.z, xb.z, a); a = fmaf(wb.w, xb.w, a);
  return a;
}
__device__ __forceinline__ float fma8(float4 wa, float4 wb, float4 xa, float4 xb, float a){
  a = fmaf(wa.x, xa.x, a); a = fmaf(wa.y, xa.y, a);
  a = fmaf(wa.z, xa.z, a); a = fmaf(wa.w, xa.w, a);
  a = fmaf(wb.x, xb.x, a); a = fmaf(wb.y, xb.y, a);
  a = fmaf(wb.z, xb.z, a); a = fmaf(wb.w, xb.w, a);
  return a;
}

// Stage W[j][nb0..nb0+17][16][8] into smem (identical layout, 1152 float4).
__device__ __forceinline__ void stage_w(const float4* __restrict__ W4, int nb0,
                                        float* __restrict__ smem, int tid){
  float4 wst[9];
  #pragma unroll
  for (int k=0;k<9;++k){
    const int idx = k*128 + tid;          // 0..1151
    const int j   = (idx >= 576) ? 1 : 0; // 576 = 18n * 32 f4
    const int r4  = idx - j*576;
    wst[k] = W4[(size_t)j*(N_*32) + (size_t)nb0*32 + r4];
  }
  #pragma unroll
  for (int k=0;k<9;++k)
    ((float4*)smem)[k*128 + tid] = wst[k];
}

// Block reduce: 2 waves x (acc0,acc1)[32] -> partial[blk][128b][32], coalesced.
__device__ __forceinline__ void reduce_store(const float* __restrict__ acc0,
                                             const float* __restrict__ acc1,
                                             float* __restrict__ smem,
                                             float* __restrict__ blk_dst,
                                             int tid, int wv, int lane){
  __syncthreads();                        // W reads done; reuse smem
  const int base = (wv*64 + lane)*65;
  #pragma unroll
  for (int k=0;k<32;++k){ smem[base + k] = acc0[k]; smem[base + 32 + k] = acc1[k]; }
  __syncthreads();
  const int l    = tid & 63;
  const int half = tid >> 6;              // 0: b_local<64 (acc0), 1: acc1
  float v[32];
  #pragma unroll
  for (int i=0;i<32;++i)
    v[i] = smem[l*65 + half*32 + i] + smem[(64 + l)*65 + half*32 + i];
  float* dst = blk_dst + tid*32;          // thread-contiguous: coalesced
  #pragma unroll
  for (int q=0;q<8;++q)
    *(float4*)(dst + q*4) = make_float4(v[q*4], v[q*4+1], v[q*4+2], v[q*4+3]);
}

// grid (NCHUNK, 2): y = b-tile (128 b), 2 waves = 2 n-chunks of 9.
__global__ __launch_bounds__(128, 2) void kpass1(const float* __restrict__ x,
                                                 const float* __restrict__ W,
                                                 float* __restrict__ partial)
{
  __shared__ float smem[8320];            // max(W stage 4608, red 2*64*65)
  const int tid  = threadIdx.x;
  const int lane = tid & 63;
  const int wv   = __builtin_amdgcn_readfirstlane(tid >> 6);
  const int b0   = blockIdx.y*128 + lane; // second elem: b0+64
  const int nb0  = blockIdx.x * NBK;
  const int n0   = nb0 + wv*NPW;

  stage_w((const float4*)W, nb0, smem, tid);

  const float* xp0 = x + ((size_t)b0*N_      + n0)*D_;
  const float* xp1 = x + ((size_t)(b0+64)*N_ + n0)*D_;
  float4 c0a = *(const float4*)(xp0);     float4 c0b = *(const float4*)(xp0+4);
  float4 c1a = *(const float4*)(xp1);     float4 c1b = *(const float4*)(xp1+4);

  float acc0[32], acc1[32];
  #pragma unroll
  for (int i=0;i<32;++i){ acc0[i]=0.f; acc1[i]=0.f; }
  __syncthreads();

  #pragma unroll 1
  for (int ni=0; ni<NPW; ++ni){
    const float4 v0a=c0a, v0b=c0b, v1a=c1a, v1b=c1b;
    if (ni < NPW-1){
      c0a = *(const float4*)(xp0 + (ni+1)*8); c0b = *(const float4*)(xp0 + (ni+1)*8 + 4);
      c1a = *(const float4*)(xp1 + (ni+1)*8); c1b = *(const float4*)(xp1 + (ni+1)*8 + 4);
    }
    const int nl = wv*NPW + ni;           // wave-uniform
    #pragma unroll
    for (int j=0;j<J_;++j){
      const float* wp = smem + (j*NBK + nl)*(E_*D_);
      #pragma unroll
      for (int e=0;e<E_;++e){
        const float4 wa = *(const float4*)(wp + e*8);
        const float4 wb = *(const float4*)(wp + e*8 + 4);
        acc0[j*16+e] = fma8(wa, wb, v0a, v0b, acc0[j*16+e]);
        acc1[j*16+e] = fma8(wa, wb, v1a, v1b, acc1[j*16+e]);
      }
    }
  }
  reduce_store(acc0, acc1, smem,
               partial + (size_t)(blockIdx.x*2 + blockIdx.y)*4096, tid, wv, lane);
}

__global__ __launch_bounds__(128, 2) void kpass2(const float* __restrict__ x,
                                                 const float* __restrict__ W,
                                                 const float* __restrict__ v1,
                                                 float* __restrict__ partial)
{
  __shared__ float smem[8320];
  const int tid  = threadIdx.x;
  const int lane = tid & 63;
  const int wv   = __builtin_amdgcn_readfirstlane(tid >> 6);
  const int b0   = blockIdx.y*128 + lane;
  const int nb0  = blockIdx.x * NBK;
  const int n0   = nb0 + wv*NPW;

  stage_w((const float4*)W, nb0, smem, tid);

  float vv0[32], vv1[32];
  {
    const float4* vp0 = (const float4*)(v1 + (size_t)b0*32);
    const float4* vp1 = (const float4*)(v1 + (size_t)(b0+64)*32);
    #pragma unroll
    for (int q=0;q<8;++q){
      const float4 a = vp0[q]; vv0[q*4]=a.x; vv0[q*4+1]=a.y; vv0[q*4+2]=a.z; vv0[q*4+3]=a.w;
      const float4 c = vp1[q]; vv1[q*4]=c.x; vv1[q*4+1]=c.y; vv1[q*4+2]=c.z; vv1[q*4+3]=c.w;
    }
  }

  const float* xp0 = x + ((size_t)b0*N_      + n0)*D_;
  const float* xp1 = x + ((size_t)(b0+64)*N_ + n0)*D_;
  float4 c0a = *(const float4*)(xp0);     float4 c0b = *(const float4*)(xp0+4);
  float4 c1a = *(const float4*)(xp1);     float4 c1b = *(const float4*)(xp1+4);

  float acc0[32], acc1[32];
  #pragma unroll
  for (int i=0;i<32;++i){ acc0[i]=0.f; acc1[i]=0.f; }
  __syncthreads();

  #pragma unroll 1
  for (int ni=0; ni<NPW; ++ni){
    const float4 v0a=c0a, v0b=c0b, v1a=c1a, v1b=c1b;
    if (ni < NPW-1){
      c0a = *(const float4*)(xp0 + (ni+1)*8); c0b = *(const float4*)(xp0 + (ni+1)*8 + 4);
      c1a = *(const float4*)(xp1 + (ni+1)*8); c1b = *(const float4*)(xp1 + (ni+1)*8 + 4);
    }
    const int nl = wv*NPW + ni;
    float u0[32], u1[32];
    #pragma unroll
    for (int j=0;j<J_;++j){
      const float* wp = smem + (j*NBK + nl)*(E_*D_);
      #pragma unroll
      for (int e=0;e<E_;++e){
        const float4 wa = *(const float4*)(wp + e*8);
        const float4 wb = *(const float4*)(wp + e*8 + 4);
        u0[j*16+e] = dot8(wa, wb, v0a, v0b);
        u1[j*16+e] = dot8(wa, wb, v1a, v1b);
      }
    }
    float l00=0.f, l01=0.f, l10=0.f, l11=0.f;
    #pragma unroll
    for (int e=0;e<E_;++e){
      l00 = fmaf(vv0[e],    u0[e],    l00);
      l01 = fmaf(vv0[16+e], u0[16+e], l01);
      l10 = fmaf(vv1[e],    u1[e],    l10);
      l11 = fmaf(vv1[16+e], u1[16+e], l11);
    }
    const float c00 = 1.f/(1.f + __expf(l01 - l00));   // softmax over 2 caps
    const float c01 = 1.f - c00;
    const float c10 = 1.f/(1.f + __expf(l11 - l10));
    const float c11 = 1.f - c10;
    #pragma unroll
    for (int e=0;e<E_;++e){
      acc0[e]    = fmaf(c00, u0[e],    acc0[e]);
      acc0[16+e] = fmaf(c01, u0[16+e], acc0[16+e]);
      acc1[e]    = fmaf(c10, u1[e],    acc1[e]);
      acc1[16+e] = fmaf(c11, u1[16+e], acc1[16+e]);
    }
  }
  reduce_store(acc0, acc1, smem,
               partial + (size_t)(blockIdx.x*2 + blockIdx.y)*4096, tid, wv, lane);
}

// Fused reduce (sum NCHUNK chunk-partials) + squash (16-lane shfl butterfly).
// t = b*32 + j*16 + e; partial chunk (x, y=b>>7) at offset x*8192 + y*4096.
template<bool HALF>
__global__ __launch_bounds__(256) void kred(const float* __restrict__ partial,
                                            float* __restrict__ dst)
{
  const int t = blockIdx.x*256 + threadIdx.x;     // grid 32 -> 8192
  const float* p = partial + (size_t)(t >> 12)*4096 + (t & 4095);
  float s = 0.f;
  #pragma unroll 8
  for (int cx=0; cx<NCHUNK; ++cx) s += p[(size_t)cx*8192];
  if (HALF) s *= 0.5f;
  float n2 = s*s;
  #pragma unroll
  for (int m=1; m<16; m<<=1) n2 += __shfl_xor(n2, m);
  const float f = (n2/(1.f+n2)) * rsqrtf(n2 + 1e-9f);
  dst[t] = s * f;
}

// ---------------- fallback: R5 monolithic (no ws) ----------------
#define NT 512
__global__ __launch_bounds__(NT) void kmono(const float* __restrict__ x,
                                            const float* __restrict__ W,
                                            float* __restrict__ out)
{
  const int b    = blockIdx.x;
  const int tid  = threadIdx.x;
  const int wv   = tid >> 6;
  const int lane = tid & 63;
  __shared__ float wred[8*33];
  __shared__ float vsh[32];

  float acc[32];
  #pragma unroll
  for (int i=0;i<32;++i) acc[i]=0.f;
  for (int n = tid; n < N_; n += NT){
    const float4 xa = *(const float4*)(x + ((size_t)b*N_ + n)*D_);
    const float4 xb = *(const float4*)(x + ((size_t)b*N_ + n)*D_ + 4);
    #pragma unroll
    for (int j=0;j<J_;++j){
      const float* wp = W + ((size_t)j*N_ + n)*(E_*D_);
      #pragma unroll
      for (int e=0;e<E_;++e){
        const float4 wa = *(const float4*)(wp + e*8);
        const float4 wb = *(const float4*)(wp + e*8 + 4);
        acc[j*16+e] = fma8(wa, wb, xa, xb, acc[j*16+e]);
      }
    }
  }
  #pragma unroll
  for (int i=0;i<32;++i){
    float v = acc[i];
    #pragma unroll
    for (int off=32; off; off>>=1) v += __shfl_xor(v, off);
    acc[i] = v;
  }
  if (lane == 0){
    #pragma unroll
    for (int i=0;i<32;++i) wred[wv*33 + i] = acc[i];
  }
  __syncthreads();
  if (tid < 32){
    float s = 0.f;
    #pragma unroll
    for (int w=0;w<8;++w) s += wred[w*33 + tid];
    wred[tid] = 0.5f * s;
  }
  __syncthreads();
  if (tid < 32){
    const int j = tid >> 4; float n2 = 0.f;
    #pragma unroll
    for (int e=0;e<16;++e){ const float sv = wred[j*16+e]; n2 = fmaf(sv,sv,n2); }
    vsh[tid] = wred[tid] * (n2/(1.f+n2)) * rsqrtf(n2 + 1e-9f);
  }
  __syncthreads();
  float vv[32];
  #pragma unroll
  for (int i=0;i<32;++i) vv[i] = vsh[i];

  #pragma unroll
  for (int i=0;i<32;++i) acc[i]=0.f;
  for (int n = tid; n < N_; n += NT){
    const float4 xa = *(const float4*)(x + ((size_t)b*N_ + n)*D_);
    const float4 xb = *(const float4*)(x + ((size_t)b*N_ + n)*D_ + 4);
    float u[32];
    #pragma unroll
    for (int j=0;j<J_;++j){
      const float* wp = W + ((size_t)j*N_ + n)*(E_*D_);
      #pragma unroll
      for (int e=0;e<E_;++e){
        const float4 wa = *(const float4*)(wp + e*8);
        const float4 wb = *(const float4*)(wp + e*8 + 4);
        u[j*16+e] = dot8(wa, wb, xa, xb);
      }
    }
    float l0=0.f, l1=0.f;
    #pragma unroll
    for (int e=0;e<16;++e){ l0 = fmaf(vv[e],u[e],l0); l1 = fmaf(vv[16+e],u[16+e],l1); }
    const float c0 = 1.f/(1.f + __expf(l1 - l0));
    const float c1 = 1.f - c0;
    #pragma unroll
    for (int e=0;e<16;++e){ acc[e] = fmaf(c0,u[e],acc[e]); acc[16+e] = fmaf(c1,u[16+e],acc[16+e]); }
  }
  #pragma unroll
  for (int i=0;i<32;++i){
    float v = acc[i];
    #pragma unroll
    for (int off=32; off; off>>=1) v += __shfl_xor(v, off);
    acc[i] = v;
  }
  __syncthreads();
  if (lane == 0){
    #pragma unroll
    for (int i=0;i<32;++i) wred[wv*33 + i] = acc[i];
  }
  __syncthreads();
  if (tid < 32){
    float s = 0.f;
    #pragma unroll
    for (int w=0;w<8;++w) s += wred[w*33 + tid];
    wred[tid] = s;
  }
  __syncthreads();
  if (tid < 32){
    const int j = tid >> 4; float n2 = 0.f;
    #pragma unroll
    for (int e=0;e<16;++e){ const float sv = wred[j*16+e]; n2 = fmaf(sv,sv,n2); }
    out[(size_t)b*32 + tid] = wred[tid] * (n2/(1.f+n2)) * rsqrtf(n2 + 1e-9f);
  }
}

extern "C" void kernel_launch(void* const* d_in, const int* in_sizes, int n_in,
                              void* d_out, int out_size, void* d_ws, size_t ws_size,
                              hipStream_t stream)
{
  const float* x = (const float*)d_in[0];   // [256,6912,8]
  const float* W = (const float*)d_in[1];   // [2,6912,16,8]
  if (n_in >= 2 && in_sizes[0] < in_sizes[1]){
    x = (const float*)d_in[1]; W = (const float*)d_in[0];
  }
  float* out = (float*)d_out;               // fp32 [256,2,16]

  // v1 (8192) + partials (768 blocks * 4096) ~ 12.6 MB
  const size_t need_main = (size_t)(8192 + 768*4096) * sizeof(float);

  if (ws_size >= need_main){
    float* wsf     = (float*)d_ws;
    float* v1      = wsf;           // 8192 floats
    float* partial = wsf + 8192;    // 768*4096 floats
    kpass1<<<dim3(NCHUNK,2), 128, 0, stream>>>(x, W, partial);
    kred<true ><<<32, 256, 0, stream>>>(partial, v1);
    kpass2<<<dim3(NCHUNK,2), 128, 0, stream>>>(x, W, v1, partial);
    kred<false><<<32, 256, 0, stream>>>(partial, out);
  } else {
    kmono<<<B_, NT, 0, stream>>>(x, W, out);
  }
}